// Round 12
// baseline (183.848 us; speedup 1.0000x reference)
//
#include <hip/hip_runtime.h>
#include <math.h>

#define BB 64
#define RR 36
#define WW 50
#define DD 1024
#define EPSF 1e-8f

#define GM 2304   // 64*36
#define GN 3200   // 64*50
#define GK 1024

typedef __attribute__((ext_vector_type(8))) short bf16x8;
typedef __attribute__((ext_vector_type(4))) float f32x4;

#define GLL(src, dst) __builtin_amdgcn_global_load_lds( \
    (const __attribute__((address_space(1))) void*)(src), \
    (__attribute__((address_space(3))) void*)(dst), 16, 0, 0)

__device__ __forceinline__ unsigned short f2bf(float x) {
    unsigned int u = __float_as_uint(x);
    unsigned int r = (u + 0x7fffu + ((u >> 16) & 1u)) >> 16;   // RTN-even
    return (unsigned short)r;
}
__device__ __forceinline__ float bf2f(unsigned short h) {
    return __uint_as_float(((unsigned int)h) << 16);
}

// Phase 1: blocks [0, GM+GN) = prep; blocks [GM+GN, +512) = gram k-slice MFMA.
__global__ __launch_bounds__(256) void phase1_kernel(
        const float* __restrict__ imgs, const float* __restrict__ caps,
        unsigned short* __restrict__ Ah, unsigned short* __restrict__ Al,
        unsigned short* __restrict__ Bh, unsigned short* __restrict__ Bl,
        float* __restrict__ invI, float* __restrict__ invC,
        float* __restrict__ Gp) {
    int bid = blockIdx.x, tid = threadIdx.x;
    if (bid < GM + GN) {
        const float* X;
        unsigned short *H, *L;
        float* invN;
        size_t r;
        if (bid < GM) { X = imgs; H = Ah; L = Al; invN = invI; r = bid; }
        else { X = caps; H = Bh; L = Bl; invN = invC; r = bid - GM; }
        size_t idx = r * 256 + tid;
        float4 v = ((const float4*)X)[idx];
        float f[4] = {v.x, v.y, v.z, v.w};
        ushort4 hh, ll;
        unsigned short* hp = (unsigned short*)&hh;
        unsigned short* lp = (unsigned short*)&ll;
        float ss = 0.f;
        #pragma unroll
        for (int j = 0; j < 4; j++) {
            unsigned short hb = f2bf(f[j]);
            hp[j] = hb;
            lp[j] = f2bf(f[j] - bf2f(hb));
            ss = fmaf(f[j], f[j], ss);
        }
        ((ushort4*)H)[idx] = hh;
        ((ushort4*)L)[idx] = ll;
        #pragma unroll
        for (int off = 32; off > 0; off >>= 1) ss += __shfl_down(ss, off, 64);
        __shared__ float part[4];
        if ((tid & 63) == 0) part[tid >> 6] = ss;
        __syncthreads();
        if (tid == 0) {
            float t = part[0] + part[1] + part[2] + part[3];
            invN[r] = 1.0f / (sqrtf(t) + EPSF);
        }
    } else {
        int q = bid - (GM + GN);
        int c = q >> 3, kq = q & 7;
        __shared__ __align__(16) unsigned short sH[4][64 * 32], sL[4][64 * 32];
        int lane = tid & 63, wv = tid >> 6;
        int fm = lane & 15;
        int row = tid >> 2;
        int kg = (tid & 3) * 8;
        int sslot = ((tid & 3) ^ ((row >> 1) & 3)) * 8;
        int grow = c * WW + row;
        if (grow > GN - 1) grow = GN - 1;   // clamp; garbage annihilated in epi
        const float* src = caps + (size_t)grow * DD + kq * 128;
        #pragma unroll
        for (int c32 = 0; c32 < 4; c32++) {
            float4 v0 = *(const float4*)(src + c32 * 32 + kg);
            float4 v1 = *(const float4*)(src + c32 * 32 + kg + 4);
            float f[8] = {v0.x, v0.y, v0.z, v0.w, v1.x, v1.y, v1.z, v1.w};
            ushort4 h0, h1, l0, l1;
            unsigned short* hp0 = (unsigned short*)&h0;
            unsigned short* hp1 = (unsigned short*)&h1;
            unsigned short* lp0 = (unsigned short*)&l0;
            unsigned short* lp1 = (unsigned short*)&l1;
            #pragma unroll
            for (int j = 0; j < 4; j++) {
                unsigned short hb = f2bf(f[j]);
                hp0[j] = hb; lp0[j] = f2bf(f[j] - bf2f(hb));
                unsigned short hb2 = f2bf(f[j + 4]);
                hp1[j] = hb2; lp1[j] = f2bf(f[j + 4] - bf2f(hb2));
            }
            int off = row * 32 + sslot;
            *(ushort4*)&sH[c32][off] = h0;
            *(ushort4*)&sH[c32][off + 4] = h1;
            *(ushort4*)&sL[c32][off] = l0;
            *(ushort4*)&sL[c32][off + 4] = l1;
        }
        __syncthreads();
        f32x4 acc[4] = {};
        int fkA = ((lane >> 4) ^ ((fm >> 1) & 3)) * 8;
        #pragma unroll
        for (int ks = 0; ks < 4; ks++) {
            int offa = (wv * 16 + fm) * 32 + fkA;
            bf16x8 ah = *(const bf16x8*)&sH[ks][offa];
            bf16x8 al = *(const bf16x8*)&sL[ks][offa];
            #pragma unroll
            for (int t = 0; t < 4; t++) {
                int offb = (t * 16 + fm) * 32 + fkA;
                bf16x8 bh = *(const bf16x8*)&sH[ks][offb];
                bf16x8 bl = *(const bf16x8*)&sL[ks][offb];
                acc[t] = __builtin_amdgcn_mfma_f32_16x16x32_bf16(ah, bh, acc[t], 0, 0, 0);
                acc[t] = __builtin_amdgcn_mfma_f32_16x16x32_bf16(ah, bl, acc[t], 0, 0, 0);
                acc[t] = __builtin_amdgcn_mfma_f32_16x16x32_bf16(al, bh, acc[t], 0, 0, 0);
            }
        }
        float* dst = Gp + ((size_t)kq * BB + c) * 4096;
        int row0 = wv * 16 + (lane >> 4) * 4;
        #pragma unroll
        for (int t = 0; t < 4; t++)
            #pragma unroll
            for (int v = 0; v < 4; v++)
                dst[(row0 + v) * 64 + t * 16 + fm] = acc[t][v];
    }
}

// Phase 2: blocks [0,64) = g2sum; blocks [64, 64+900) = gemm 128x128 tile
// over HALF of K (kq = 0/1), partials to T + kq*GM*GN. 900 blocks -> every CU
// holds >=3 blocks so barrier drains overlap MFMA on sibling blocks.
__global__ __launch_bounds__(256) void phase2_kernel(
        const unsigned short* __restrict__ Ah, const unsigned short* __restrict__ Al,
        const unsigned short* __restrict__ Bh, const unsigned short* __restrict__ Bl,
        const float* __restrict__ Gp, unsigned short* __restrict__ Gh,
        unsigned short* __restrict__ Gl, float* __restrict__ T) {
    int bid = blockIdx.x, tid = threadIdx.x;
    if (bid < BB) {
        int c = bid;
        for (int t = tid; t < 4096; t += 256) {
            float s = 0.f;
            #pragma unroll
            for (int q = 0; q < 8; q++) s += Gp[((size_t)q * BB + c) * 4096 + t];
            unsigned short h = f2bf(s);
            Gh[(size_t)c * 4096 + t] = h;
            Gl[(size_t)c * 4096 + t] = f2bf(s - bf2f(h));
        }
        return;
    }
    int q = bid - BB;
    int kq = (q >= 450) ? 1 : 0;
    int tt = q - kq * 450;
    int m0 = (tt / 25) * 128, n0 = (tt % 25) * 128;

    __shared__ __align__(16) unsigned short sAh[128 * 32], sAl[128 * 32];
    __shared__ __align__(16) unsigned short sBh[128 * 32], sBl[128 * 32];
    int lane = tid & 63, wv = tid >> 6;
    int rw = (wv & 1) * 64;
    int cw = (wv >> 1) * 64;

    f32x4 acc[4][4] = {};

    int srow = lane >> 2;
    // GLL dst is lane-ordered; XOR swizzle applied on the GLOBAL k-group
    int scol = (((lane & 3) ^ ((srow >> 1) & 3))) * 8;
    int fm = lane & 15;
    int fkS = ((lane >> 4) ^ ((fm >> 1) & 3)) * 8;

    int kend = kq * 512 + 512;
    for (int k0 = kq * 512; k0 < kend; k0 += 32) {
        __syncthreads();
        #pragma unroll
        for (int j = 0; j < 2; j++) {
            int seg = wv * 2 + j;
            int row = seg * 16 + srow;
            size_t ga = (size_t)(m0 + row) * GK + k0 + scol;
            size_t gb = (size_t)(n0 + row) * GK + k0 + scol;
            GLL(Ah + ga, sAh + seg * 512);
            GLL(Al + ga, sAl + seg * 512);
            GLL(Bh + gb, sBh + seg * 512);
            GLL(Bl + gb, sBl + seg * 512);
        }
        __syncthreads();

        bf16x8 fah[4], fal[4], fbh[4], fbl[4];
        #pragma unroll
        for (int t = 0; t < 4; t++) {
            int offa = (rw + t * 16 + fm) * 32 + fkS;
            int offb = (cw + t * 16 + fm) * 32 + fkS;
            fah[t] = *(const bf16x8*)&sAh[offa];
            fal[t] = *(const bf16x8*)&sAl[offa];
            fbh[t] = *(const bf16x8*)&sBh[offb];
            fbl[t] = *(const bf16x8*)&sBl[offb];
        }
        #pragma unroll
        for (int mt = 0; mt < 4; mt++)
            #pragma unroll
            for (int nt = 0; nt < 4; nt++) {
                acc[mt][nt] = __builtin_amdgcn_mfma_f32_16x16x32_bf16(
                    fah[mt], fbh[nt], acc[mt][nt], 0, 0, 0);
                acc[mt][nt] = __builtin_amdgcn_mfma_f32_16x16x32_bf16(
                    fah[mt], fbl[nt], acc[mt][nt], 0, 0, 0);
                acc[mt][nt] = __builtin_amdgcn_mfma_f32_16x16x32_bf16(
                    fal[mt], fbh[nt], acc[mt][nt], 0, 0, 0);
            }
    }

    float* Tout = T + (size_t)kq * GM * GN;
    int orow0 = m0 + rw + (lane >> 4) * 4;
    int ocol0 = n0 + cw + fm;
    #pragma unroll
    for (int mt = 0; mt < 4; mt++)
        #pragma unroll
        for (int nt = 0; nt < 4; nt++)
            #pragma unroll
            for (int v = 0; v < 4; v++)
                Tout[(size_t)(orow0 + mt * 16 + v) * GN + ocol0 + nt * 16] = acc[mt][nt][v];
}

// Epilogue: one block per (c, i); grid 64x64. T = sum of two K-half partials.
#define MST 72   // sM row stride in ushorts (144 B, 16B-aligned)
__global__ __launch_bounds__(256) void epi_kernel(
        const float* __restrict__ T,
        const unsigned short* __restrict__ Gh, const unsigned short* __restrict__ Gl,
        const int* __restrict__ img_lens, const int* __restrict__ cap_lens,
        const float* __restrict__ alpha,
        const float* __restrict__ invI, const float* __restrict__ invC,
        float* __restrict__ out) {
    int c = blockIdx.x, i = blockIdx.y;
    __shared__ __align__(16) unsigned short sGh[64 * 64], sGl[64 * 64];
    __shared__ __align__(16) unsigned short sMh[48 * MST], sMl[48 * MST];
    __shared__ __align__(16) float Hsh[36][68];
    __shared__ float numSh[36];
    __shared__ float part[36][4];

    int tid = threadIdx.x;
    int lane = tid & 63, wv = tid >> 6;
    int fm = lane & 15, fk8 = (lane >> 4) * 8;
    int hf = lane >> 5, l5 = lane & 31;

    {   // swizzled store: row r slot kg -> LDS slot kg ^ (r&7)
        const uint4* gh = (const uint4*)(Gh + (size_t)c * 4096);
        const uint4* gl = (const uint4*)(Gl + (size_t)c * 4096);
        int rowg = tid >> 3, kg = tid & 7;
        int d = (rowg << 3) | (kg ^ (rowg & 7));
        ((uint4*)sGh)[d] = gh[tid];
        ((uint4*)sGh)[d + 256] = gh[tid + 256];
        ((uint4*)sGl)[d] = gl[tid];
        ((uint4*)sGl)[d + 256] = gl[tid + 256];
    }
    for (int t = tid; t < 12 * MST; t += 256) {
        sMh[36 * MST + t] = 0; sMl[36 * MST + t] = 0;
    }
    __syncthreads();

    bf16x8 gfh[2], gfl[2];
    #pragma unroll
    for (int ks = 0; ks < 2; ks++) {
        int kg8 = ks * 4 + (lane >> 4);
        int off = (wv * 16 + fm) * 64 + (kg8 ^ (fm & 7)) * 8;
        gfh[ks] = *(const bf16x8*)&sGh[off];
        gfl[ks] = *(const bf16x8*)&sGl[off];
    }

    int lc = cap_lens[c], li = img_lens[i];
    float a_mix = 1.0f / (1.0f + __expf(-alpha[0]));
    float oma = 1.0f - a_mix;
    float invC0 = invC[c * WW + l5];
    float invC1 = (l5 + 32 < WW) ? invC[c * WW + l5 + 32] : 0.f;
    bool v0 = l5 < lc, v1 = (l5 + 32) < lc;

    for (int r = wv * 2 + hf; r < RR; r += 8) {
        float inv_ir = invI[i * RR + r];
        const float* Trow = T + (size_t)(i * RR + r) * GN + c * WW;
        const float* Trow2 = Trow + (size_t)GM * GN;
        float T0 = Trow[l5] + Trow2[l5];
        float T1 = (l5 + 32 < WW) ? (Trow[l5 + 32] + Trow2[l5 + 32]) : 0.f;
        float S0 = v0 ? (T0 * inv_ir * invC0) : -2.f;
        float S1 = v1 ? (T1 * inv_ir * invC1) : -2.f;
        float mv; int mi;
        if (S1 > S0) { mv = S1; mi = l5 + 32; } else { mv = S0; mi = l5; }
        #pragma unroll
        for (int m = 1; m < 32; m <<= 1) {
            float ov = __shfl_xor(mv, m, 32);
            int oi = __shfl_xor(mi, m, 32);
            if (ov > mv || (ov == mv && oi < mi)) { mv = ov; mi = oi; }
        }
        float e0 = v0 ? __expf((S0 - mv) * 10.f) : 0.f;
        float e1 = v1 ? __expf((S1 - mv) * 10.f) : 0.f;
        float ss = e0 + e1, nm = fmaf(e0, T0, e1 * T1);
        #pragma unroll
        for (int m = 1; m < 32; m <<= 1) {
            ss += __shfl_xor(ss, m, 32);
            nm += __shfl_xor(nm, m, 32);
        }
        float Tmi = (mi < 32) ? __shfl(T0, mi, 32) : __shfl(T1, mi - 32, 32);
        float scale = a_mix / ss;
        float m0 = e0 * scale + (l5 == mi ? oma : 0.f);
        float m1 = e1 * scale + (l5 + 32 == mi ? oma : 0.f);
        if (l5 == 0) numSh[r] = fmaf(nm, scale, oma * Tmi);
        unsigned short h0 = f2bf(m0), h1 = f2bf(m1);
        sMh[r * MST + l5] = h0;
        sMl[r * MST + l5] = f2bf(m0 - bf2f(h0));
        sMh[r * MST + l5 + 32] = h1;
        sMl[r * MST + l5 + 32] = f2bf(m1 - bf2f(h1));
    }
    __syncthreads();

    int quad4 = (lane >> 4) * 4;
    #pragma unroll
    for (int mt = 0; mt < 3; mt++) {
        f32x4 acc = {0.f, 0.f, 0.f, 0.f};
        #pragma unroll
        for (int ks = 0; ks < 2; ks++) {
            int off = (mt * 16 + fm) * MST + ks * 32 + fk8;
            bf16x8 mh = *(const bf16x8*)&sMh[off];
            bf16x8 ml = *(const bf16x8*)&sMl[off];
            acc = __builtin_amdgcn_mfma_f32_16x16x32_bf16(mh, gfh[ks], acc, 0, 0, 0);
            acc = __builtin_amdgcn_mfma_f32_16x16x32_bf16(mh, gfl[ks], acc, 0, 0, 0);
            acc = __builtin_amdgcn_mfma_f32_16x16x32_bf16(ml, gfh[ks], acc, 0, 0, 0);
        }
        #pragma unroll
        for (int v = 0; v < 4; v++) {
            int row = mt * 16 + quad4 + v;
            if (row < RR) Hsh[row][wv * 16 + fm] = acc[v];
        }
    }
    __syncthreads();

    if (tid < 144) {
        int r = tid >> 2, j = tid & 3;
        const bf16x8* mh = (const bf16x8*)&sMh[r * MST + j * 16];
        const bf16x8* ml = (const bf16x8*)&sMl[r * MST + j * 16];
        float p = 0.f;
        #pragma unroll
        for (int g = 0; g < 2; g++) {
            bf16x8 h8 = mh[g], l8 = ml[g];
            #pragma unroll
            for (int qq = 0; qq < 8; qq++) {
                float m = bf2f((unsigned short)h8[qq]) + bf2f((unsigned short)l8[qq]);
                p = fmaf(m, Hsh[r][j * 16 + g * 8 + qq], p);
            }
        }
        part[r][j] = p;
    }
    __syncthreads();
    if (tid < RR) {
        float den2 = part[tid][0] + part[tid][1] + part[tid][2] + part[tid][3];
        float res = (tid < li) ? (numSh[tid] / (sqrtf(den2) + EPSF)) : -1.0f;
        out[((size_t)i * BB + c) * RR + tid] = res;
    }
}

extern "C" void kernel_launch(void* const* d_in, const int* in_sizes, int n_in,
                              void* d_out, int out_size, void* d_ws, size_t ws_size,
                              hipStream_t stream) {
    const float* imgs = (const float*)d_in[0];
    const float* caps = (const float*)d_in[1];
    const int* img_lens = (const int*)d_in[2];
    const int* cap_lens = (const int*)d_in[3];
    const float* alpha = (const float*)d_in[4];
    float* out = (float*)d_out;

    float* ws = (float*)d_ws;
    float* invI = ws;                              // 2304
    float* invC = ws + BB * RR;                    // 3200
    float* T = invC + BB * WW;                     // 2 * 7372800 (K-half partials)
    unsigned short* Ah = (unsigned short*)(T + 2 * (size_t)GM * GN);
    unsigned short* Al = Ah + (size_t)GM * GK;
    unsigned short* Bh = Al + (size_t)GM * GK;
    unsigned short* Bl = Bh + (size_t)GN * GK;
    unsigned short* Gbh = Bl + (size_t)GN * GK;    // 64*4096
    unsigned short* Gbl = Gbh + (size_t)BB * 4096;
    float* Gp = (float*)(Gbl + (size_t)BB * 4096); // 8*64*4096 fp32 partials

    phase1_kernel<<<GM + GN + 512, 256, 0, stream>>>(
        imgs, caps, Ah, Al, Bh, Bl, invI, invC, Gp);
    phase2_kernel<<<BB + 900, 256, 0, stream>>>(
        Ah, Al, Bh, Bl, Gp, Gbh, Gbl, T);
    epi_kernel<<<dim3(BB, BB), 256, 0, stream>>>(
        T, Gbh, Gbl, img_lens, cap_lens, alpha, invI, invC, out);
}

// Round 13
// 159.326 us; speedup vs baseline: 1.1539x; 1.1539x over previous
//
#include <hip/hip_runtime.h>
#include <math.h>

#define BB 64
#define RR 36
#define WW 50
#define DD 1024
#define EPSF 1e-8f

#define GM 2304   // 64*36
#define GN 3200   // 64*50
#define GK 1024

typedef __attribute__((ext_vector_type(8))) short bf16x8;
typedef __attribute__((ext_vector_type(4))) float f32x4;

#define GLL(src, dst) __builtin_amdgcn_global_load_lds( \
    (const __attribute__((address_space(1))) void*)(src), \
    (__attribute__((address_space(3))) void*)(dst), 16, 0, 0)

__device__ __forceinline__ unsigned short f2bf(float x) {
    unsigned int u = __float_as_uint(x);
    unsigned int r = (u + 0x7fffu + ((u >> 16) & 1u)) >> 16;   // RTN-even
    return (unsigned short)r;
}
__device__ __forceinline__ float bf2f(unsigned short h) {
    return __uint_as_float(((unsigned int)h) << 16);
}

// Phase 1: blocks [0, GM+GN) = prep; blocks [GM+GN, +512) = gram k-slice MFMA.
__global__ __launch_bounds__(256) void phase1_kernel(
        const float* __restrict__ imgs, const float* __restrict__ caps,
        unsigned short* __restrict__ Ah, unsigned short* __restrict__ Al,
        unsigned short* __restrict__ Bh, unsigned short* __restrict__ Bl,
        float* __restrict__ invI, float* __restrict__ invC,
        float* __restrict__ Gp) {
    int bid = blockIdx.x, tid = threadIdx.x;
    if (bid < GM + GN) {
        const float* X;
        unsigned short *H, *L;
        float* invN;
        size_t r;
        if (bid < GM) { X = imgs; H = Ah; L = Al; invN = invI; r = bid; }
        else { X = caps; H = Bh; L = Bl; invN = invC; r = bid - GM; }
        size_t idx = r * 256 + tid;
        float4 v = ((const float4*)X)[idx];
        float f[4] = {v.x, v.y, v.z, v.w};
        ushort4 hh, ll;
        unsigned short* hp = (unsigned short*)&hh;
        unsigned short* lp = (unsigned short*)&ll;
        float ss = 0.f;
        #pragma unroll
        for (int j = 0; j < 4; j++) {
            unsigned short hb = f2bf(f[j]);
            hp[j] = hb;
            lp[j] = f2bf(f[j] - bf2f(hb));
            ss = fmaf(f[j], f[j], ss);
        }
        ((ushort4*)H)[idx] = hh;
        ((ushort4*)L)[idx] = ll;
        #pragma unroll
        for (int off = 32; off > 0; off >>= 1) ss += __shfl_down(ss, off, 64);
        __shared__ float part[4];
        if ((tid & 63) == 0) part[tid >> 6] = ss;
        __syncthreads();
        if (tid == 0) {
            float t = part[0] + part[1] + part[2] + part[3];
            invN[r] = 1.0f / (sqrtf(t) + EPSF);
        }
    } else {
        int q = bid - (GM + GN);
        int c = q >> 3, kq = q & 7;
        __shared__ __align__(16) unsigned short sH[4][64 * 32], sL[4][64 * 32];
        int lane = tid & 63, wv = tid >> 6;
        int fm = lane & 15;
        int row = tid >> 2;
        int kg = (tid & 3) * 8;
        int sslot = ((tid & 3) ^ ((row >> 1) & 3)) * 8;
        int grow = c * WW + row;
        if (grow > GN - 1) grow = GN - 1;   // clamp; garbage annihilated in epi
        const float* src = caps + (size_t)grow * DD + kq * 128;
        #pragma unroll
        for (int c32 = 0; c32 < 4; c32++) {
            float4 v0 = *(const float4*)(src + c32 * 32 + kg);
            float4 v1 = *(const float4*)(src + c32 * 32 + kg + 4);
            float f[8] = {v0.x, v0.y, v0.z, v0.w, v1.x, v1.y, v1.z, v1.w};
            ushort4 h0, h1, l0, l1;
            unsigned short* hp0 = (unsigned short*)&h0;
            unsigned short* hp1 = (unsigned short*)&h1;
            unsigned short* lp0 = (unsigned short*)&l0;
            unsigned short* lp1 = (unsigned short*)&l1;
            #pragma unroll
            for (int j = 0; j < 4; j++) {
                unsigned short hb = f2bf(f[j]);
                hp0[j] = hb; lp0[j] = f2bf(f[j] - bf2f(hb));
                unsigned short hb2 = f2bf(f[j + 4]);
                hp1[j] = hb2; lp1[j] = f2bf(f[j + 4] - bf2f(hb2));
            }
            int off = row * 32 + sslot;
            *(ushort4*)&sH[c32][off] = h0;
            *(ushort4*)&sH[c32][off + 4] = h1;
            *(ushort4*)&sL[c32][off] = l0;
            *(ushort4*)&sL[c32][off + 4] = l1;
        }
        __syncthreads();
        f32x4 acc[4] = {};
        int fkA = ((lane >> 4) ^ ((fm >> 1) & 3)) * 8;
        #pragma unroll
        for (int ks = 0; ks < 4; ks++) {
            int offa = (wv * 16 + fm) * 32 + fkA;
            bf16x8 ah = *(const bf16x8*)&sH[ks][offa];
            bf16x8 al = *(const bf16x8*)&sL[ks][offa];
            #pragma unroll
            for (int t = 0; t < 4; t++) {
                int offb = (t * 16 + fm) * 32 + fkA;
                bf16x8 bh = *(const bf16x8*)&sH[ks][offb];
                bf16x8 bl = *(const bf16x8*)&sL[ks][offb];
                acc[t] = __builtin_amdgcn_mfma_f32_16x16x32_bf16(ah, bh, acc[t], 0, 0, 0);
                acc[t] = __builtin_amdgcn_mfma_f32_16x16x32_bf16(ah, bl, acc[t], 0, 0, 0);
                acc[t] = __builtin_amdgcn_mfma_f32_16x16x32_bf16(al, bh, acc[t], 0, 0, 0);
            }
        }
        float* dst = Gp + ((size_t)kq * BB + c) * 4096;
        int row0 = wv * 16 + (lane >> 4) * 4;
        #pragma unroll
        for (int t = 0; t < 4; t++)
            #pragma unroll
            for (int v = 0; v < 4; v++)
                dst[(row0 + v) * 64 + t * 16 + fm] = acc[t][v];
    }
}

// Phase 2: blocks [0,64) = g2sum (bf16 G, single precision level — den^2 path
// tolerates bf16); blocks [64, 64+450) = gemm 128x128 tile, full K, swizzled.
__global__ __launch_bounds__(256) void phase2_kernel(
        const unsigned short* __restrict__ Ah, const unsigned short* __restrict__ Al,
        const unsigned short* __restrict__ Bh, const unsigned short* __restrict__ Bl,
        const float* __restrict__ Gp, unsigned short* __restrict__ Gh,
        float* __restrict__ T) {
    int bid = blockIdx.x, tid = threadIdx.x;
    if (bid < BB) {
        int c = bid;
        for (int t = tid; t < 4096; t += 256) {
            float s = 0.f;
            #pragma unroll
            for (int q = 0; q < 8; q++) s += Gp[((size_t)q * BB + c) * 4096 + t];
            Gh[(size_t)c * 4096 + t] = f2bf(s);
        }
        return;
    }
    int q = bid - BB;
    int m0 = (q / 25) * 128, n0 = (q % 25) * 128;

    __shared__ __align__(16) unsigned short sAh[128 * 32], sAl[128 * 32];
    __shared__ __align__(16) unsigned short sBh[128 * 32], sBl[128 * 32];
    int lane = tid & 63, wv = tid >> 6;
    int rw = (wv & 1) * 64;
    int cw = (wv >> 1) * 64;

    f32x4 acc[4][4] = {};

    int srow = lane >> 2;
    // GLL dst is lane-ordered; XOR swizzle applied on the GLOBAL k-group
    int scol = (((lane & 3) ^ ((srow >> 1) & 3))) * 8;
    int fm = lane & 15;
    int fkS = ((lane >> 4) ^ ((fm >> 1) & 3)) * 8;

    for (int k0 = 0; k0 < GK; k0 += 32) {
        __syncthreads();
        #pragma unroll
        for (int j = 0; j < 2; j++) {
            int seg = wv * 2 + j;
            int row = seg * 16 + srow;
            size_t ga = (size_t)(m0 + row) * GK + k0 + scol;
            size_t gb = (size_t)(n0 + row) * GK + k0 + scol;
            GLL(Ah + ga, sAh + seg * 512);
            GLL(Al + ga, sAl + seg * 512);
            GLL(Bh + gb, sBh + seg * 512);
            GLL(Bl + gb, sBl + seg * 512);
        }
        __syncthreads();

        bf16x8 fah[4], fal[4], fbh[4], fbl[4];
        #pragma unroll
        for (int t = 0; t < 4; t++) {
            int offa = (rw + t * 16 + fm) * 32 + fkS;
            int offb = (cw + t * 16 + fm) * 32 + fkS;
            fah[t] = *(const bf16x8*)&sAh[offa];
            fal[t] = *(const bf16x8*)&sAl[offa];
            fbh[t] = *(const bf16x8*)&sBh[offb];
            fbl[t] = *(const bf16x8*)&sBl[offb];
        }
        #pragma unroll
        for (int mt = 0; mt < 4; mt++)
            #pragma unroll
            for (int nt = 0; nt < 4; nt++) {
                acc[mt][nt] = __builtin_amdgcn_mfma_f32_16x16x32_bf16(
                    fah[mt], fbh[nt], acc[mt][nt], 0, 0, 0);
                acc[mt][nt] = __builtin_amdgcn_mfma_f32_16x16x32_bf16(
                    fah[mt], fbl[nt], acc[mt][nt], 0, 0, 0);
                acc[mt][nt] = __builtin_amdgcn_mfma_f32_16x16x32_bf16(
                    fal[mt], fbh[nt], acc[mt][nt], 0, 0, 0);
            }
    }

    int orow0 = m0 + rw + (lane >> 4) * 4;
    int ocol0 = n0 + cw + fm;
    #pragma unroll
    for (int mt = 0; mt < 4; mt++)
        #pragma unroll
        for (int nt = 0; nt < 4; nt++)
            #pragma unroll
            for (int v = 0; v < 4; v++)
                T[(size_t)(orow0 + mt * 16 + v) * GN + ocol0 + nt * 16] = acc[mt][nt][v];
}

// Epilogue: one block per (c, i); single-pass bf16 den^2 path (num stays fp32).
#define MST 72   // sM row stride in ushorts (144 B, 16B-aligned)
__global__ __launch_bounds__(256) void epi_kernel(
        const float* __restrict__ T, const unsigned short* __restrict__ Gh,
        const int* __restrict__ img_lens, const int* __restrict__ cap_lens,
        const float* __restrict__ alpha,
        const float* __restrict__ invI, const float* __restrict__ invC,
        float* __restrict__ out) {
    int c = blockIdx.x, i = blockIdx.y;
    __shared__ __align__(16) unsigned short sGh[64 * 64];
    __shared__ __align__(16) unsigned short sMh[48 * MST];
    __shared__ __align__(16) float Hsh[36][68];
    __shared__ float numSh[36];
    __shared__ float part[36][4];

    int tid = threadIdx.x;
    int lane = tid & 63, wv = tid >> 6;
    int fm = lane & 15, fk8 = (lane >> 4) * 8;
    int hf = lane >> 5, l5 = lane & 31;

    {   // swizzled store: row r slot kg -> LDS slot kg ^ (r&7)
        const uint4* gh = (const uint4*)(Gh + (size_t)c * 4096);
        int rowg = tid >> 3, kg = tid & 7;
        int d = (rowg << 3) | (kg ^ (rowg & 7));
        ((uint4*)sGh)[d] = gh[tid];
        ((uint4*)sGh)[d + 256] = gh[tid + 256];
    }
    for (int t = tid; t < 12 * MST; t += 256) sMh[36 * MST + t] = 0;
    __syncthreads();

    bf16x8 gfh[2];
    #pragma unroll
    for (int ks = 0; ks < 2; ks++) {
        int kg8 = ks * 4 + (lane >> 4);
        int off = (wv * 16 + fm) * 64 + (kg8 ^ (fm & 7)) * 8;
        gfh[ks] = *(const bf16x8*)&sGh[off];
    }

    int lc = cap_lens[c], li = img_lens[i];
    float a_mix = 1.0f / (1.0f + __expf(-alpha[0]));
    float oma = 1.0f - a_mix;
    float invC0 = invC[c * WW + l5];
    float invC1 = (l5 + 32 < WW) ? invC[c * WW + l5 + 32] : 0.f;
    bool v0 = l5 < lc, v1 = (l5 + 32) < lc;

    for (int r = wv * 2 + hf; r < RR; r += 8) {
        float inv_ir = invI[i * RR + r];
        const float* Trow = T + (size_t)(i * RR + r) * GN + c * WW;
        float T0 = Trow[l5];
        float T1 = (l5 + 32 < WW) ? Trow[l5 + 32] : 0.f;
        float S0 = v0 ? (T0 * inv_ir * invC0) : -2.f;
        float S1 = v1 ? (T1 * inv_ir * invC1) : -2.f;
        float mv; int mi;
        if (S1 > S0) { mv = S1; mi = l5 + 32; } else { mv = S0; mi = l5; }
        #pragma unroll
        for (int m = 1; m < 32; m <<= 1) {
            float ov = __shfl_xor(mv, m, 32);
            int oi = __shfl_xor(mi, m, 32);
            if (ov > mv || (ov == mv && oi < mi)) { mv = ov; mi = oi; }
        }
        float e0 = v0 ? __expf((S0 - mv) * 10.f) : 0.f;
        float e1 = v1 ? __expf((S1 - mv) * 10.f) : 0.f;
        float ss = e0 + e1, nm = fmaf(e0, T0, e1 * T1);
        #pragma unroll
        for (int m = 1; m < 32; m <<= 1) {
            ss += __shfl_xor(ss, m, 32);
            nm += __shfl_xor(nm, m, 32);
        }
        float Tmi = (mi < 32) ? __shfl(T0, mi, 32) : __shfl(T1, mi - 32, 32);
        float scale = a_mix / ss;
        float m0 = e0 * scale + (l5 == mi ? oma : 0.f);
        float m1 = e1 * scale + (l5 + 32 == mi ? oma : 0.f);
        if (l5 == 0) numSh[r] = fmaf(nm, scale, oma * Tmi);
        sMh[r * MST + l5] = f2bf(m0);
        sMh[r * MST + l5 + 32] = f2bf(m1);
    }
    __syncthreads();

    int quad4 = (lane >> 4) * 4;
    #pragma unroll
    for (int mt = 0; mt < 3; mt++) {
        f32x4 acc = {0.f, 0.f, 0.f, 0.f};
        #pragma unroll
        for (int ks = 0; ks < 2; ks++) {
            int off = (mt * 16 + fm) * MST + ks * 32 + fk8;
            bf16x8 mh = *(const bf16x8*)&sMh[off];
            acc = __builtin_amdgcn_mfma_f32_16x16x32_bf16(mh, gfh[ks], acc, 0, 0, 0);
        }
        #pragma unroll
        for (int v = 0; v < 4; v++) {
            int row = mt * 16 + quad4 + v;
            if (row < RR) Hsh[row][wv * 16 + fm] = acc[v];
        }
    }
    __syncthreads();

    if (tid < 144) {
        int r = tid >> 2, j = tid & 3;
        const bf16x8* mh = (const bf16x8*)&sMh[r * MST + j * 16];
        float p = 0.f;
        #pragma unroll
        for (int g = 0; g < 2; g++) {
            bf16x8 h8 = mh[g];
            #pragma unroll
            for (int qq = 0; qq < 8; qq++) {
                float m = bf2f((unsigned short)h8[qq]);
                p = fmaf(m, Hsh[r][j * 16 + g * 8 + qq], p);
            }
        }
        part[r][j] = p;
    }
    __syncthreads();
    if (tid < RR) {
        float den2 = part[tid][0] + part[tid][1] + part[tid][2] + part[tid][3];
        float res = (tid < li) ? (numSh[tid] / (sqrtf(den2) + EPSF)) : -1.0f;
        out[((size_t)i * BB + c) * RR + tid] = res;
    }
}

extern "C" void kernel_launch(void* const* d_in, const int* in_sizes, int n_in,
                              void* d_out, int out_size, void* d_ws, size_t ws_size,
                              hipStream_t stream) {
    const float* imgs = (const float*)d_in[0];
    const float* caps = (const float*)d_in[1];
    const int* img_lens = (const int*)d_in[2];
    const int* cap_lens = (const int*)d_in[3];
    const float* alpha = (const float*)d_in[4];
    float* out = (float*)d_out;

    float* ws = (float*)d_ws;
    float* invI = ws;                              // 2304
    float* invC = ws + BB * RR;                    // 3200
    float* T = invC + BB * WW;                     // 7372800
    unsigned short* Ah = (unsigned short*)(T + (size_t)GM * GN);
    unsigned short* Al = Ah + (size_t)GM * GK;
    unsigned short* Bh = Al + (size_t)GM * GK;
    unsigned short* Bl = Bh + (size_t)GN * GK;
    unsigned short* Gbh = Bl + (size_t)GN * GK;    // 64*4096
    float* Gp = (float*)(Gbh + (size_t)BB * 4096); // 8*64*4096 fp32 partials

    phase1_kernel<<<GM + GN + 512, 256, 0, stream>>>(
        imgs, caps, Ah, Al, Bh, Bl, invI, invC, Gp);
    phase2_kernel<<<BB + 450, 256, 0, stream>>>(
        Ah, Al, Bh, Bl, Gp, Gbh, T);
    epi_kernel<<<dim3(BB, BB), 256, 0, stream>>>(
        T, Gbh, img_lens, cap_lens, alpha, invI, invC, out);
}